// Round 6
// baseline (501.777 us; speedup 1.0000x reference)
//
#include <hip/hip_runtime.h>

// ---------------- problem constants ----------------
constexpr int CB = 64;          // batch
constexpr int CHH = 14, CWW = 14;
constexpr int CN = 196;         // CHH*CWW
constexpr int CC = 1024;        // channels
constexpr int CROWS = CB * CN;  // 12544
constexpr int CKW = 8;          // rfft bins along W

// twiddles: cos/sin(2*pi*m/14), m=0..13
constexpr float C14[14] = {
  1.0f, 0.9009688679024191f, 0.6234898018587336f, 0.2225209339563144f,
  -0.2225209339563144f, -0.6234898018587336f, -0.9009688679024191f, -1.0f,
  -0.9009688679024191f, -0.6234898018587336f, -0.2225209339563144f,
  0.2225209339563144f, 0.6234898018587336f, 0.9009688679024191f };
constexpr float S14[14] = {
  0.0f, 0.4338837391175581f, 0.7818314824680298f, 0.9749279121818236f,
  0.9749279121818236f, 0.7818314824680298f, 0.4338837391175581f, 0.0f,
  -0.4338837391175581f, -0.7818314824680298f, -0.9749279121818236f,
  -0.9749279121818236f, -0.7818314824680298f, -0.4338837391175581f };

typedef __attribute__((ext_vector_type(8))) short bf16x8;
typedef __attribute__((ext_vector_type(4))) float f32x4;

__device__ __forceinline__ unsigned short f2bf(float f) {
  unsigned u = __builtin_bit_cast(unsigned, f);
  u += 0x7FFFu + ((u >> 16) & 1u);   // RNE
  return (unsigned short)(u >> 16);
}
__device__ __forceinline__ float bf2f(unsigned short h) {
  return __builtin_bit_cast(float, (unsigned)h << 16);
}

__device__ __forceinline__ void gload_lds16(const void* g, void* l) {
  __builtin_amdgcn_global_load_lds(
      (const __attribute__((address_space(1))) void*)g,
      (__attribute__((address_space(3))) void*)l, 16, 0, 0);
}

#define WAITV(N)  asm volatile("s_waitcnt vmcnt(" #N ")" ::: "memory")
#define SBAR()    asm volatile("s_barrier" ::: "memory")

// ---------------- LayerNorm over C=1024 (one block per row) ----------------
template<int OUTBF>
__global__ __launch_bounds__(256)
void ln_kernel(const float* __restrict__ in, const float* __restrict__ gam,
               const float* __restrict__ bet, float* __restrict__ outf,
               unsigned short* __restrict__ outb)
{
  const int row = blockIdx.x;
  const int t = threadIdx.x;
  const float4 v = *(const float4*)(in + (size_t)row * CC + t * 4);
  float s  = v.x + v.y + v.z + v.w;
  float s2 = v.x*v.x + v.y*v.y + v.z*v.z + v.w*v.w;
  #pragma unroll
  for (int o = 32; o > 0; o >>= 1) { s += __shfl_down(s, o); s2 += __shfl_down(s2, o); }
  __shared__ float red[8];
  const int wid = t >> 6, lane = t & 63;
  if (lane == 0) { red[wid] = s; red[4 + wid] = s2; }
  __syncthreads();
  s  = red[0] + red[1] + red[2] + red[3];
  s2 = red[4] + red[5] + red[6] + red[7];
  const float mean = s * (1.0f / CC);
  const float var  = s2 * (1.0f / CC) - mean * mean;
  const float r = rsqrtf(var + 1e-5f);
  const float4 g4 = *(const float4*)(gam + t * 4);
  const float4 b4 = *(const float4*)(bet + t * 4);
  const float o0 = (v.x - mean) * r * g4.x + b4.x;
  const float o1 = (v.y - mean) * r * g4.y + b4.y;
  const float o2 = (v.z - mean) * r * g4.z + b4.z;
  const float o3 = (v.w - mean) * r * g4.w + b4.w;
  if (OUTBF) {
    ushort4 p; p.x = f2bf(o0); p.y = f2bf(o1); p.z = f2bf(o2); p.w = f2bf(o3);
    *(ushort4*)(outb + (size_t)row * CC + t * 4) = p;
  } else {
    *(float4*)(outf + (size_t)row * CC + t * 4) = make_float4(o0, o1, o2, o3);
  }
}

// ---------------- rfft along W: [B,H,W,C] real -> [B,H,8,C] complex ----------------
__global__ __launch_bounds__(256)
void fft_w_fwd(const float* __restrict__ y, float* __restrict__ Ar, float* __restrict__ Ai)
{
  const int t = threadIdx.x;
  const int bid = blockIdx.x;      // ((b*14)+h)*4 + cc
  const int cc = bid & 3;
  const int tmp = bid >> 2;
  const int h = tmp % 14;
  const int b = tmp / 14;
  const int c = cc * 256 + t;
  const size_t base = ((size_t)b * CN + (size_t)h * CWW) * CC + c;
  float v[14];
  #pragma unroll
  for (int w = 0; w < 14; w++) v[w] = y[base + (size_t)w * CC];
  const size_t obase = (((size_t)b * CHH + h) * CKW) * CC + c;
  #pragma unroll
  for (int kw = 0; kw < 8; kw++) {
    float sr = 0.f, si = 0.f;
    #pragma unroll
    for (int w = 0; w < 14; w++) {
      const int m = (w * kw) % 14;
      sr += v[w] * C14[m];
      si -= v[w] * S14[m];
    }
    Ar[obase + (size_t)kw * CC] = sr;
    Ai[obase + (size_t)kw * CC] = si;
  }
}

// ---------------- fft along H + complex filter + ifft along H ----------------
__global__ __launch_bounds__(256)
void fft_h_filt(const float* __restrict__ Ar, const float* __restrict__ Ai,
                const float* __restrict__ cw, float* __restrict__ Br, float* __restrict__ Bi)
{
  const int t = threadIdx.x;
  const int bid = blockIdx.x;      // ((b*8)+kw)*4 + cc
  const int cc = bid & 3;
  const int tmp = bid >> 2;
  const int kw = tmp & 7;
  const int b = tmp >> 3;
  const int c = cc * 256 + t;
  const size_t base = (((size_t)b * CHH) * CKW + kw) * CC + c;   // h stride = CKW*CC
  float ar[14], ai[14];
  #pragma unroll
  for (int h = 0; h < 14; h++) {
    ar[h] = Ar[base + (size_t)h * (CKW * CC)];
    ai[h] = Ai[base + (size_t)h * (CKW * CC)];
  }
  float fr[14], fi[14];
  #pragma unroll
  for (int kh = 0; kh < 14; kh++) {
    float yr = 0.f, yi = 0.f;
    #pragma unroll
    for (int h = 0; h < 14; h++) {
      const int m = (h * kh) % 14;
      yr += ar[h] * C14[m] + ai[h] * S14[m];
      yi += ai[h] * C14[m] - ar[h] * S14[m];
    }
    const size_t widx = (((size_t)kh * CKW + kw) * CC + c) * 2;
    const float wr = cw[widx], wi = cw[widx + 1];
    fr[kh] = yr * wr - yi * wi;
    fi[kh] = yr * wi + yi * wr;
  }
  #pragma unroll
  for (int h = 0; h < 14; h++) {
    float sr = 0.f, si = 0.f;
    #pragma unroll
    for (int kh = 0; kh < 14; kh++) {
      const int m = (h * kh) % 14;
      sr += fr[kh] * C14[m] - fi[kh] * S14[m];
      si += fr[kh] * S14[m] + fi[kh] * C14[m];
    }
    Br[base + (size_t)h * (CKW * CC)] = sr;
    Bi[base + (size_t)h * (CKW * CC)] = si;
  }
}

// ---------------- irfft along W (c2r: imag of DC/Nyquist ignored) ----------------
__global__ __launch_bounds__(256)
void fft_w_inv(const float* __restrict__ Br, const float* __restrict__ Bi, float* __restrict__ y2)
{
  const int t = threadIdx.x;
  const int bid = blockIdx.x;
  const int cc = bid & 3;
  const int tmp = bid >> 2;
  const int h = tmp % 14;
  const int b = tmp / 14;
  const int c = cc * 256 + t;
  const size_t ibase = (((size_t)b * CHH + h) * CKW) * CC + c;
  float br[8], bi[8];
  #pragma unroll
  for (int k = 0; k < 8; k++) {
    br[k] = Br[ibase + (size_t)k * CC];
    bi[k] = Bi[ibase + (size_t)k * CC];
  }
  const size_t obase = ((size_t)b * CN + (size_t)h * CWW) * CC + c;
  #pragma unroll
  for (int w = 0; w < 14; w++) {
    float s = br[0] + ((w & 1) ? -br[7] : br[7]);
    #pragma unroll
    for (int k = 1; k < 7; k++) {
      const int m = (w * k) % 14;
      s += 2.0f * (br[k] * C14[m] - bi[k] * S14[m]);
    }
    y2[obase + (size_t)w * CC] = s * (1.0f / 196.0f);   // ortho fwd*inv = 1/196
  }
}

// ---------------- transpose fp32 [R,Cc] -> bf16 [Cc,R] ----------------
__global__ __launch_bounds__(256)
void transpose_f32_bf16(const float* __restrict__ in, unsigned short* __restrict__ out,
                        int R, int Ccols)
{
  __shared__ float tile[32][33];
  const int tx = threadIdx.x & 31;
  const int ty = threadIdx.x >> 5;     // 0..7
  const int cb = blockIdx.x * 32;
  const int rb = blockIdx.y * 32;
  #pragma unroll
  for (int i = 0; i < 32; i += 8)
    tile[ty + i][tx] = in[(size_t)(rb + ty + i) * Ccols + cb + tx];
  __syncthreads();
  #pragma unroll
  for (int i = 0; i < 32; i += 8)
    out[(size_t)(cb + ty + i) * R + rb + tx] = f2bf(tile[tx][ty + i]);
}

// ---------------- 256x256 bf16 GEMM, compiler-pipelined K-tile ----------------
// C[M,N] = A[M,K] * BT[N,K]^T, +bias, optional exact GELU, bf16 out.
// 512 thr = 8 waves (2M x 4N); BK=64. LDS: 4 disjoint 32KB arrays (A0/A1/B0/B1).
// Per K-tile T: read buf[T&1], stage T+1 into buf[(T+1)&1] (disjoint arrays).
// Sync: ONE vmcnt(0)+s_barrier at tile entry (publishes the staged tile across
// waves). NO other waits/pins inside the tile: ds_reads are plain C++ shared
// loads, so the compiler emits fine-grained counted lgkmcnt between ds_read
// and dependent MFMA and software-pipelines the body (m97/G7 behavior; pinning
// with lgkmcnt(0)+sched_barrier was the R2-R5 ~6900cy/tile stall).
#define STAGE(REG, TILE_, DST) do {                                           \
  const unsigned short* _g = (((REG) < 2) ? A : BT);                          \
  const int _gb = (((REG) < 2) ? brow : bcol);                                \
  int _r0, _r1;                                                               \
  if ((REG) == 0)      { _r0 = vA;       _r1 = 128 + vA; }                    \
  else if ((REG) == 1) { _r0 = 64 + vA;  _r1 = 192 + vA; }                    \
  else if ((REG) == 2) { _r0 = ((vA>>5)<<6) + (vA&31);      _r1 = _r0 + 128; }\
  else                 { _r0 = ((vA>>5)<<6) + 32 + (vA&31); _r1 = _r0 + 128; }\
  const int _gc = (TILE_) * 64 + cl;                                          \
  gload_lds16(_g + (size_t)(_gb + _r0) * K + _gc, (DST) + _r0 * 128 + dcol16);\
  gload_lds16(_g + (size_t)(_gb + _r1) * K + _gc, (DST) + _r1 * 128 + dcol16);\
} while (0)

#define LOADA(CAarr, MH) do {                                                 \
  _Pragma("unroll")                                                           \
  for (int mf = 0; mf < 4; ++mf) {                                            \
    const int row = wm * 128 + (MH) * 64 + mf * 16 + lrow;                    \
    const int sw = (row & 7) << 4;                                            \
    af[mf][0] = *(const bf16x8*)((CAarr) + row * 128 + ((0  | dq) ^ sw));     \
    af[mf][1] = *(const bf16x8*)((CAarr) + row * 128 + ((64 | dq) ^ sw));     \
  }                                                                           \
} while (0)

#define LOADB(CBarr, DEST, NH) do {                                           \
  _Pragma("unroll")                                                           \
  for (int nf = 0; nf < 2; ++nf) {                                            \
    const int row = wn * 64 + ((NH) * 2 + nf) * 16 + lrow;                    \
    const int sw = (row & 7) << 4;                                            \
    DEST[nf][0] = *(const bf16x8*)((CBarr) + row * 128 + ((0  | dq) ^ sw));   \
    DEST[nf][1] = *(const bf16x8*)((CBarr) + row * 128 + ((64 | dq) ^ sw));   \
  }                                                                           \
} while (0)

#define MFMA8(MH, NH, BFR) do {                                               \
  _Pragma("unroll")                                                           \
  for (int ks = 0; ks < 2; ++ks)                                              \
    _Pragma("unroll")                                                         \
    for (int mf = 0; mf < 4; ++mf)                                            \
      _Pragma("unroll")                                                       \
      for (int nf = 0; nf < 2; ++nf)                                          \
        acc[(MH) * 4 + mf][(NH) * 2 + nf] = __builtin_amdgcn_mfma_f32_16x16x32_bf16( \
            af[mf][ks], BFR[nf][ks], acc[(MH) * 4 + mf][(NH) * 2 + nf], 0, 0, 0); \
} while (0)

#define TILEBODY(TT, CAarr, CBarr, NAarr, NBarr) do {                         \
  WAITV(0);                                                                   \
  SBAR();                                                                     \
  if ((TT) + 1 < NT) {                                                        \
    STAGE(0, (TT)+1, NAarr);                                                  \
    STAGE(2, (TT)+1, NBarr);                                                  \
    STAGE(3, (TT)+1, NBarr);                                                  \
    STAGE(1, (TT)+1, NAarr);                                                  \
  }                                                                           \
  LOADB(CBarr, bf0, 0);                                                       \
  LOADB(CBarr, bf1, 1);                                                       \
  LOADA(CAarr, 0);                                                            \
  MFMA8(0, 0, bf0);                                                           \
  MFMA8(0, 1, bf1);                                                           \
  LOADA(CAarr, 1);                                                            \
  MFMA8(1, 0, bf0);                                                           \
  MFMA8(1, 1, bf1);                                                           \
} while (0)

template<int DO_GELU>
__global__ __launch_bounds__(512, 2)
void gemm256(const unsigned short* __restrict__ A, const unsigned short* __restrict__ BT,
             const float* __restrict__ bias, unsigned short* __restrict__ C,
             int M, int N, int K)
{
  __shared__ __align__(16) short A0s[256 * 64];
  __shared__ __align__(16) short A1s[256 * 64];
  __shared__ __align__(16) short B0s[256 * 64];
  __shared__ __align__(16) short B1s[256 * 64];
  char* a0 = (char*)A0s; char* a1 = (char*)A1s;
  char* b0 = (char*)B0s; char* b1 = (char*)B1s;

  const int t = threadIdx.x;
  const int wid = t >> 6, lane = t & 63;
  const int wm = wid >> 2, wn = wid & 3;
  const int lrow = lane & 15, qk = lane >> 4;
  const int dq = qk << 4;

  // T1: bijective XCD swizzle (m204) + GROUP=4 along N
  const int nbx = N >> 8, nby = M >> 8;
  const int nwg = nbx * nby;
  const int orig = blockIdx.x;
  const int q8 = nwg >> 3, r8 = nwg & 7, xcd = orig & 7, lid = orig >> 3;
  const int wg = (xcd < r8 ? xcd * (q8 + 1) : r8 * (q8 + 1) + (xcd - r8) * q8) + lid;
  const int gw = 4 * nby;
  const int gid = wg / gw, rem = wg % gw;
  const int bx = gid * 4 + (rem & 3);
  const int by = rem >> 2;
  const int brow = by << 8, bcol = bx << 8;
  const int NT = K >> 6;

  // staging per-thread constants
  const int vA = t >> 3;                       // 0..63
  const int cl = ((t ^ (t >> 3)) & 7) << 3;    // inverse-swizzled element col
  const int dcol16 = (t & 7) << 4;             // byte offset within LDS row

  f32x4 acc[8][4] = {};
  bf16x8 af[4][2], bf0[2][2], bf1[2][2];

  // prologue: stage K-tile 0 into buf0 (tile-0's vmcnt(0) at loop entry syncs it)
  STAGE(0, 0, a0); STAGE(2, 0, b0); STAGE(3, 0, b0); STAGE(1, 0, a0);

  for (int T = 0; T < NT; T += 2) {
    TILEBODY(T,     a0, b0, a1, b1);
    TILEBODY(T + 1, a1, b1, a0, b0);
  }

  // epilogue: bias (+GELU) + bf16 store
  #pragma unroll
  for (int mf = 0; mf < 8; ++mf) {
    #pragma unroll
    for (int nf = 0; nf < 4; ++nf) {
      const int ccol = bcol + wn * 64 + nf * 16 + lrow;
      const float bb = bias[ccol];
      #pragma unroll
      for (int j = 0; j < 4; ++j) {
        const int r = brow + wm * 128 + mf * 16 + qk * 4 + j;
        float v = acc[mf][nf][j] + bb;
        if (DO_GELU) v = 0.5f * v * (1.0f + erff(v * 0.70710678118654752f));
        C[(size_t)r * N + ccol] = f2bf(v);
      }
    }
  }
}

// ---------------- FEM: 3 blockwise instance-norm gates fused + residual ----------------
__device__ __forceinline__ void fem_block(unsigned short* col, int t,
                                          int h0, int nh, int w0, int nw)
{
  float s = 0.f, s2 = 0.f;
  for (int ih = 0; ih < nh; ih++)
    for (int iw = 0; iw < nw; iw++) {
      const float v = bf2f(col[((h0 + ih) * 14 + w0 + iw) * 128 + t]);
      s += v; s2 += v * v;
    }
  const float inv = 1.0f / (float)(nh * nw);
  const float m = s * inv;
  const float var = s2 * inv - m * m;
  const float r = rsqrtf(var + 1e-5f);
  for (int ih = 0; ih < nh; ih++)
    for (int iw = 0; iw < nw; iw++) {
      const int idx = ((h0 + ih) * 14 + w0 + iw) * 128 + t;
      const float v = bf2f(col[idx]);
      const float a = 1.0f / (1.0f + __expf(-(v - m) * r));
      col[idx] = f2bf(0.5f * v * (1.0f + a));
    }
}

__global__ __launch_bounds__(128)
void fem_kernel(const unsigned short* __restrict__ z, const float* __restrict__ x,
                float* __restrict__ out)
{
  __shared__ unsigned short buf[CN * 128];   // 50,176 B; thread-private columns
  const int t = threadIdx.x;
  const int b = blockIdx.x >> 3;
  const int cc = blockIdx.x & 7;
  const int c = cc * 128 + t;
  const size_t base = (size_t)b * CN * CC + c;
  #pragma unroll 4
  for (int n = 0; n < CN; n++) buf[n * 128 + t] = z[base + (size_t)n * CC];
  // s = 3: 5x5 blocks, row/col starts {0,3,6,9,12}, lens {3,3,3,3,2}
  const int st3[5] = {0, 3, 6, 9, 12};
  const int ln3[5] = {3, 3, 3, 3, 2};
  for (int i = 0; i < 5; i++)
    for (int j = 0; j < 5; j++)
      fem_block(buf, t, st3[i], ln3[i], st3[j], ln3[j]);
  // s = 7: 2x2 blocks of 7x7
  for (int i = 0; i < 2; i++)
    for (int j = 0; j < 2; j++)
      fem_block(buf, t, i * 7, 7, j * 7, 7);
  // s = 14: whole field
  fem_block(buf, t, 0, 14, 0, 14);
  #pragma unroll 4
  for (int n = 0; n < CN; n++)
    out[base + (size_t)n * CC] = x[base + (size_t)n * CC] + bf2f(buf[n * 128 + t]);
}

// ---------------- launch ----------------
extern "C" void kernel_launch(void* const* d_in, const int* in_sizes, int n_in,
                              void* d_out, int out_size, void* d_ws, size_t ws_size,
                              hipStream_t stream) {
  const float* x     = (const float*)d_in[0];
  const float* ln1_g = (const float*)d_in[1];
  const float* ln1_b = (const float*)d_in[2];
  const float* cw    = (const float*)d_in[3];
  const float* ln2_g = (const float*)d_in[4];
  const float* ln2_b = (const float*)d_in[5];
  const float* fc1_w = (const float*)d_in[6];
  const float* fc1_b = (const float*)d_in[7];
  const float* fc2_w = (const float*)d_in[8];
  const float* fc2_b = (const float*)d_in[9];
  float* out = (float*)d_out;
  char* ws = (char*)d_ws;

  // arena (total 161.5 MB); d_out doubles as fp32 scratch for y1/y2
  const size_t SZ_A = (size_t)CB * CHH * CKW * CC * 4;       // 29,360,128 B
  float* Ar = (float*)(ws);
  float* Ai = (float*)(ws + SZ_A);
  float* Br = (float*)(ws + 2 * SZ_A);
  float* Bi = (float*)(ws + 3 * SZ_A);
  unsigned short* A1   = (unsigned short*)(ws);                        // after FFT done
  unsigned short* W1T  = (unsigned short*)(ws + SZ_A);                 // [4096,1024] bf16
  unsigned short* W2T  = (unsigned short*)(ws + SZ_A + (size_t)4096 * 1024 * 2); // [1024,4096]
  unsigned short* Hmid = (unsigned short*)(ws + 2 * SZ_A);             // [12544,4096] bf16
  unsigned short* Z    = (unsigned short*)(ws);                        // [12544,1024] bf16

  // 1. LN1: x -> y1 (in d_out)
  ln_kernel<0><<<CROWS, 256, 0, stream>>>(x, ln1_g, ln1_b, out, nullptr);
  // 2. rfft along W
  fft_w_fwd<<<CB * CHH * 4, 256, 0, stream>>>(out, Ar, Ai);
  // 3. fft along H + filter + ifft along H
  fft_h_filt<<<CB * CKW * 4, 256, 0, stream>>>(Ar, Ai, cw, Br, Bi);
  // 4. irfft along W -> y2 (in d_out)
  fft_w_inv<<<CB * CHH * 4, 256, 0, stream>>>(Br, Bi, out);
  // 5. LN2 -> bf16 A1
  ln_kernel<1><<<CROWS, 256, 0, stream>>>(out, ln2_g, ln2_b, nullptr, A1);
  // 6. weight prep (FFT intermediates dead)
  transpose_f32_bf16<<<dim3(4096 / 32, 1024 / 32), 256, 0, stream>>>(fc1_w, W1T, 1024, 4096);
  transpose_f32_bf16<<<dim3(1024 / 32, 4096 / 32), 256, 0, stream>>>(fc2_w, W2T, 4096, 1024);
  // 7. GEMM1 + bias + exact GELU -> Hmid bf16 (grid 16x49=784)
  gemm256<1><<<dim3(784), 512, 0, stream>>>(A1, W1T, fc1_b, Hmid, CROWS, 4096, 1024);
  // 8. GEMM2 + bias -> Z bf16 (grid 4x49=196)
  gemm256<0><<<dim3(196), 512, 0, stream>>>(Hmid, W2T, fc2_b, Z, CROWS, 1024, 4096);
  // 9. FEM x3 fused + residual -> out
  fem_kernel<<<CB * 8, 128, 0, stream>>>(Z, x, out);
}